// Round 11
// baseline (262.035 us; speedup 1.0000x reference)
//
#include <hip/hip_runtime.h>

#define EPS_C 0.05f
#define BLOCK 512     /* 8 waves */
#define NBLK  256     /* 1 block per CU, forced by LDS footprint */
#define BPB   131072  /* elems per block: 8 waves x 16 units x 1024 */
#define NCNT  32      /* spread barrier counters */

typedef int i4 __attribute__((ext_vector_type(4)));
typedef float f4 __attribute__((ext_vector_type(4)));
typedef unsigned int uu2 __attribute__((ext_vector_type(2)));

__global__ void k_zero(unsigned int* __restrict__ p) {
  if (threadIdx.x < NCNT) p[threadIdx.x] = 0u;
}

// Build the 6-entry change table (thread 0 only; caller syncs).
__device__ __forceinline__ void build_table(const float* bd_p, const float* d_p,
                                            const float* s_p, const float* inc_p,
                                            const float* bi_p, float* cs) {
  if (threadIdx.x == 0) {
    float bd = *bd_p, d = *d_p, s = *s_p, inc = *inc_p, bi = *bi_p;
    cs[0] = 0.0f;                                   // cat 0 (unused)
    cs[1] = fminf(bd, fminf(0.0f, d)) - EPS_C;      // big decrease
    cs[2] = fminf(fmaxf(d, bd + EPS_C), -EPS_C);    // decrease (clip)
    cs[3] = s;                                      // same
    cs[4] = fminf(fmaxf(inc, EPS_C), bi - EPS_C);   // increase (clip)
    cs[5] = fmaxf(bi, fmaxf(0.0f, inc) + EPS_C);    // big increase
    cs[6] = 0.0f; cs[7] = 0.0f;
  }
}

// One-pass scan, 256 blocks (1/CU by LDS), pack staged in LDS (no spills,
// no pack HBM round-trip). Plain launch_bounds: R6/R10 showed a second arg
// makes the allocator cap at 64 VGPR and spill.
// A: NT-load 16 i4/lane/unit x16 units, nibble-pack -> LDS, unit sums in
//    VGPRs, block sum -> coarse[b] (release) + release-add cnt[b%32].
// barrier: wave 0 polls the 32 counters (acquire) until sum==NBLK.
// B: block-exclusive prefix over coarse[0..b) (1 entry/thread, b<=255).
// C: decode from LDS, 64-lane scan per 256-elem round, NT f4 stores.
__global__ __launch_bounds__(BLOCK) void k_onepass(
    const int* __restrict__ ann, const float* __restrict__ origin,
    const float* bd, const float* d, const float* s, const float* inc,
    const float* bi, float* __restrict__ out, float* __restrict__ coarse,
    unsigned int* __restrict__ cnt, int nb) {
  __shared__ uu2 lds_pk[8192];      // 64 KiB: 128 units x 64 lanes x 8 B
  __shared__ float cs[4360];        // 17 KiB: [0..7] = table; rest pads LDS
                                    //   past 80 KiB so HW fits 1 block/CU
  __shared__ float wsum[8];
  __shared__ float ws2[8];
  const int t = threadIdx.x, lane = t & 63, w = t >> 6, b = blockIdx.x;

  build_table(bd, d, s, inc, bi, cs);
  __syncthreads();

  // ---- phase A ----
  const size_t ebase = (size_t)b * BPB + (size_t)w * 16384;  // wave's 1st elem
  const i4* in4 = (const i4*)ann + (ebase >> 2) + lane;
  float usum[16];                   // per-1024-unit sums (all lanes)
#pragma unroll
  for (int u = 0; u < 16; ++u) {
    unsigned lo = 0, hi = 0;
    float sum = 0.0f;
#pragma unroll
    for (int r = 0; r < 4; ++r) {
      i4 v = __builtin_nontemporal_load(&in4[u * 256 + r * 64]);
      sum += cs[v.x] + cs[v.y] + cs[v.z] + cs[v.w];
      unsigned nib = (unsigned)v.x | ((unsigned)v.y << 4) |
                     ((unsigned)v.z << 8) | ((unsigned)v.w << 12);
      if (r & 1) { if (r < 2) lo |= nib << 16; else hi |= nib << 16; }
      else       { if (r < 2) lo |= nib;       else hi |= nib; }
    }
    lds_pk[(w * 16 + u) * 64 + lane] = (uu2){lo, hi};
#pragma unroll
    for (int off = 32; off >= 1; off >>= 1) sum += __shfl_xor(sum, off, 64);
    usum[u] = sum;
  }
  float wtot = 0.0f;
#pragma unroll
  for (int u = 0; u < 16; ++u) wtot += usum[u];
  if (lane == 0) wsum[w] = wtot;
  const float org = *origin;
  __syncthreads();
  if (t == 0) {
    float bt = 0.0f;
#pragma unroll
    for (int i = 0; i < 8; ++i) bt += wsum[i];
    __hip_atomic_store(&coarse[b], bt, __ATOMIC_RELEASE,
                       __HIP_MEMORY_SCOPE_AGENT);
    __hip_atomic_fetch_add(&cnt[b & (NCNT - 1)], 1u, __ATOMIC_RELEASE,
                           __HIP_MEMORY_SCOPE_AGENT);
  }

  // ---- grid barrier: wave 0 polls the spread counters ----
  if (w == 0) {
    for (;;) {
      unsigned c = (lane < NCNT)
          ? __hip_atomic_load(&cnt[lane], __ATOMIC_ACQUIRE,
                              __HIP_MEMORY_SCOPE_AGENT)
          : 0u;
#pragma unroll
      for (int off = 32; off >= 1; off >>= 1) c += __shfl_xor(c, off, 64);
      if (c == (unsigned)nb) break;
      __builtin_amdgcn_s_sleep(8);
    }
  }
  __syncthreads();

  // ---- phase B: block-exclusive prefix over coarse[0..b) ----
  float p = (t < b) ? __hip_atomic_load(&coarse[t], __ATOMIC_RELAXED,
                                        __HIP_MEMORY_SCOPE_AGENT)
                    : 0.0f;
#pragma unroll
  for (int off = 32; off >= 1; off >>= 1) p += __shfl_xor(p, off, 64);
  if (lane == 0) ws2[w] = p;
  __syncthreads();
  float P = org;
#pragma unroll
  for (int i = 0; i < 8; ++i) P += ws2[i];

  float wexcl = 0.0f;
#pragma unroll
  for (int i = 0; i < 8; ++i) { float wv = wsum[i]; if (i < w) wexcl += wv; }

  if (b == nb - 1 && w == 7 && lane == 0)
    out[(size_t)nb * BPB] = P + wexcl + wtot;    // out[N]

  // ---- phase C: decode + scan + NT store (no further barriers) ----
  float carry = P + wexcl;
#pragma unroll
  for (int u = 0; u < 16; ++u) {
    const uu2 pk = lds_pk[(w * 16 + u) * 64 + lane];
    float c2 = carry;
#pragma unroll
    for (int r = 0; r < 4; ++r) {
      const unsigned pw = (r < 2) ? pk.x : pk.y;
      const unsigned us = (r & 1) ? (pw >> 16) : (pw & 0xFFFFu);
      const float v0 = cs[us & 0xFu];
      const float v1 = cs[(us >> 4) & 0xFu];
      const float v2 = cs[(us >> 8) & 0xFu];
      const float v3 = cs[(us >> 12) & 0xFu];
      const float s4 = v0 + v1 + v2 + v3;
      float x = s4;                    // inclusive wave scan of 4-elem sums
#pragma unroll
      for (int off = 1; off < 64; off <<= 1) {
        float y = __shfl_up(x, off, 64);
        if (lane >= off) x += y;
      }
      const float off0 = c2 + (x - s4);
      f4 o;
      o.x = off0;
      o.y = off0 + v0;
      o.z = o.y + v1;
      o.w = o.z + v2;
      __builtin_nontemporal_store(
          o, (f4*)(out + ebase + u * 1024 + r * 256 + lane * 4));
      c2 += __shfl(x, 63, 64);
    }
    carry += usum[u];
  }
}

/* ---------------- fallback (N mismatch only): proven R7 path ---------------- */

__global__ __launch_bounds__(256) void k_pack_reduce(
    const int* __restrict__ ann, const float* bd, const float* d,
    const float* s, const float* inc, const float* bi,
    uu2* __restrict__ pack, float* __restrict__ coarse,
    float* __restrict__ fine) {
  __shared__ float cs[8];
  __shared__ float wsum[4];
  build_table(bd, d, s, inc, bi, cs);
  __syncthreads();
  const int t = threadIdx.x, lane = t & 63, w = t >> 6, b = blockIdx.x;
  const size_t ebase = (size_t)b * 8192 + (size_t)w * 2048;
  const i4* in4 = (const i4*)ann + (ebase >> 2) + lane;
  float fs[2];
#pragma unroll
  for (int u = 0; u < 2; ++u) {
    unsigned lo = 0, hi = 0;
    float sum = 0.0f;
#pragma unroll
    for (int r = 0; r < 4; ++r) {
      i4 v = __builtin_nontemporal_load(&in4[u * 256 + r * 64]);
      sum += cs[v.x] + cs[v.y] + cs[v.z] + cs[v.w];
      unsigned nib = (unsigned)v.x | ((unsigned)v.y << 4) |
                     ((unsigned)v.z << 8) | ((unsigned)v.w << 12);
      if (r & 1) { if (r < 2) lo |= nib << 16; else hi |= nib << 16; }
      else       { if (r < 2) lo |= nib;       else hi |= nib; }
    }
    pack[((size_t)b * 8 + w * 2 + u) * 64 + lane] = (uu2){lo, hi};
#pragma unroll
    for (int off = 32; off >= 1; off >>= 1) sum += __shfl_xor(sum, off, 64);
    fs[u] = sum;
  }
  if (lane == 0) {
    fine[b * 8 + w * 2 + 0] = fs[0];
    fine[b * 8 + w * 2 + 1] = fs[1];
    wsum[w] = fs[0] + fs[1];
  }
  __syncthreads();
  if (t == 0) coarse[b] = wsum[0] + wsum[1] + wsum[2] + wsum[3];
}

__global__ __launch_bounds__(256) void k_scan_out(
    const uu2* __restrict__ pack, const float* __restrict__ coarse,
    const float* __restrict__ fine, const float* __restrict__ origin,
    const float* bd, const float* d, const float* s, const float* inc,
    const float* bi, float* __restrict__ out, int nb) {
  __shared__ float cs[8];
  __shared__ float ws2[4];
  build_table(bd, d, s, inc, bi, cs);
  const int t = threadIdx.x, lane = t & 63, w = t >> 6, b = blockIdx.x;

  const uu2 pk0 = pack[((size_t)b * 8 + w * 2 + 0) * 64 + lane];
  const uu2 pk1 = pack[((size_t)b * 8 + w * 2 + 1) * 64 + lane];
  float f = (lane < 8) ? fine[b * 8 + lane] : 0.0f;
  const float org = *origin;

  float p = 0.0f;
  for (int i = t; i < b; i += 256) p += coarse[i];
#pragma unroll
  for (int off = 32; off >= 1; off >>= 1) p += __shfl_xor(p, off, 64);
  if (lane == 0) ws2[w] = p;

#pragma unroll
  for (int off = 1; off < 8; off <<= 1) {
    float y = __shfl_up(f, off, 64);
    if (lane >= off && lane < 8) f += y;
  }

  __syncthreads();
  const float P = org + ws2[0] + ws2[1] + ws2[2] + ws2[3];

  if (b == nb - 1 && w == 0 && lane == 7)
    out[(size_t)nb * 8192] = P + f;

  const uu2 pks[2] = {pk0, pk1};
#pragma unroll
  for (int h = 0; h < 2; ++h) {
    const int j = w * 2 + h;
    float carry = P + ((j > 0) ? __shfl(f, j - 1, 64) : 0.0f);
    const uu2 pk = pks[h];
    const size_t ubase = (size_t)b * 8192 + (size_t)j * 1024;
#pragma unroll
    for (int r = 0; r < 4; ++r) {
      const unsigned pw = (r < 2) ? pk.x : pk.y;
      const unsigned us = (r & 1) ? (pw >> 16) : (pw & 0xFFFFu);
      const float v0 = cs[us & 0xFu];
      const float v1 = cs[(us >> 4) & 0xFu];
      const float v2 = cs[(us >> 8) & 0xFu];
      const float v3 = cs[(us >> 12) & 0xFu];
      const float s4 = v0 + v1 + v2 + v3;
      float x = s4;
#pragma unroll
      for (int off = 1; off < 64; off <<= 1) {
        float y = __shfl_up(x, off, 64);
        if (lane >= off) x += y;
      }
      const float off0 = carry + (x - s4);
      f4 o;
      o.x = off0;
      o.y = off0 + v0;
      o.z = o.y + v1;
      o.w = o.z + v2;
      __builtin_nontemporal_store(o, (f4*)(out + ubase + r * 256 + lane * 4));
      carry += __shfl(x, 63, 64);
    }
  }
}

extern "C" void kernel_launch(void* const* d_in, const int* in_sizes, int n_in,
                              void* d_out, int out_size, void* d_ws, size_t ws_size,
                              hipStream_t stream) {
  const int*   ann    = (const int*)d_in[0];
  const float* origin = (const float*)d_in[1];
  const float* bd     = (const float*)d_in[2];
  const float* dw     = (const float*)d_in[3];
  const float* sw     = (const float*)d_in[4];
  const float* ic     = (const float*)d_in[5];
  const float* bi     = (const float*)d_in[6];
  float* out = (float*)d_out;

  const int N = in_sizes[0];                    // 2^25 = NBLK * BPB

  float* coarse = (float*)d_ws;                 // 4096 floats (both paths)
  unsigned int* cnt = (unsigned int*)(coarse + 4096);  // 32 counters
  float* fine = (float*)(cnt + NCNT);           // 32768 floats (fallback)
  uu2* pack = (uu2*)(fine + 32768);             // 16.8 MB (fallback)

  if (N == NBLK * BPB) {
    k_zero<<<1, 64, 0, stream>>>(cnt);
    k_onepass<<<NBLK, BLOCK, 0, stream>>>(ann, origin, bd, dw, sw, ic, bi,
                                          out, coarse, cnt, NBLK);
    return;
  }

  const int nb = N / 8192;
  k_pack_reduce<<<nb, 256, 0, stream>>>(ann, bd, dw, sw, ic, bi,
                                        pack, coarse, fine);
  k_scan_out<<<nb, 256, 0, stream>>>(pack, coarse, fine, origin,
                                     bd, dw, sw, ic, bi, out, nb);
}

// Round 12
// 240.383 us; speedup vs baseline: 1.0901x; 1.0901x over previous
//
#include <hip/hip_runtime.h>

#define EPS_C 0.05f
#define BLOCK 256
#define BPB   8192    /* elems per block, both kernels: 4 waves x 2 units */

typedef int i4 __attribute__((ext_vector_type(4)));
typedef float f4 __attribute__((ext_vector_type(4)));
typedef unsigned int uu2 __attribute__((ext_vector_type(2)));

// Build the 6-entry change table into LDS (thread 0 only; caller syncs).
__device__ __forceinline__ void build_table(const float* bd_p, const float* d_p,
                                            const float* s_p, const float* inc_p,
                                            const float* bi_p, float* cs) {
  if (threadIdx.x == 0) {
    float bd = *bd_p, d = *d_p, s = *s_p, inc = *inc_p, bi = *bi_p;
    cs[0] = 0.0f;                                   // cat 0 (unused)
    cs[1] = fminf(bd, fminf(0.0f, d)) - EPS_C;      // big decrease
    cs[2] = fminf(fmaxf(d, bd + EPS_C), -EPS_C);    // decrease (clip)
    cs[3] = s;                                      // same
    cs[4] = fminf(fmaxf(inc, EPS_C), bi - EPS_C);   // increase (clip)
    cs[5] = fmaxf(bi, fmaxf(0.0f, inc) + EPS_C);    // big increase
    cs[6] = 0.0f; cs[7] = 0.0f;
  }
}

// K1: block b owns 8192 elems (4 waves x 2 units x 1024). Per unit, lane l
// packs rounds r=0..3 (elems ubase + r*256 + 4l) into one uint2 -> ONE
// coalesced 8B store per unit (512B/wave). Emits per-unit fine sums and the
// block sum coarse[b]. Input loads NT (read-once; protects pack L2/L3
// residency — original session's A/B confirmed).
__global__ __launch_bounds__(BLOCK) void k_pack_reduce(
    const int* __restrict__ ann, const float* bd, const float* d,
    const float* s, const float* inc, const float* bi,
    uu2* __restrict__ pack, float* __restrict__ coarse,
    float* __restrict__ fine) {
  __shared__ float cs[8];
  __shared__ float wsum[4];
  build_table(bd, d, s, inc, bi, cs);
  __syncthreads();
  const int t = threadIdx.x, lane = t & 63, w = t >> 6, b = blockIdx.x;
  const size_t ebase = (size_t)b * BPB + (size_t)w * 2048;  // wave's first elem
  const i4* in4 = (const i4*)ann + (ebase >> 2) + lane;
  float fs[2];
#pragma unroll
  for (int u = 0; u < 2; ++u) {
    unsigned lo = 0, hi = 0;
    float sum = 0.0f;
#pragma unroll
    for (int r = 0; r < 4; ++r) {
      i4 v = __builtin_nontemporal_load(&in4[u * 256 + r * 64]);
      sum += cs[v.x] + cs[v.y] + cs[v.z] + cs[v.w];
      unsigned nib = (unsigned)v.x | ((unsigned)v.y << 4) |
                     ((unsigned)v.z << 8) | ((unsigned)v.w << 12);
      if (r & 1) { if (r < 2) lo |= nib << 16; else hi |= nib << 16; }
      else       { if (r < 2) lo |= nib;       else hi |= nib; }
    }
    pack[((size_t)b * 8 + w * 2 + u) * 64 + lane] = (uu2){lo, hi};
#pragma unroll
    for (int off = 32; off >= 1; off >>= 1) sum += __shfl_xor(sum, off, 64);
    fs[u] = sum;
  }
  if (lane == 0) {
    fine[b * 8 + w * 2 + 0] = fs[0];
    fine[b * 8 + w * 2 + 1] = fs[1];
    wsum[w] = fs[0] + fs[1];
  }
  __syncthreads();
  if (t == 0) coarse[b] = wsum[0] + wsum[1] + wsum[2] + wsum[3];
}

// K2: identical to R7 except out stores are PLAIN (A/B vs NT: fills sustain
// 6.7 TB/s with plain stores; our NT path measured ~4.8 TB/s effective).
__global__ __launch_bounds__(BLOCK) void k_scan_out(
    const uu2* __restrict__ pack, const float* __restrict__ coarse,
    const float* __restrict__ fine, const float* __restrict__ origin,
    const float* bd, const float* d, const float* s, const float* inc,
    const float* bi, float* __restrict__ out, int nb) {
  __shared__ float cs[8];
  __shared__ float ws2[4];
  build_table(bd, d, s, inc, bi, cs);
  const int t = threadIdx.x, lane = t & 63, w = t >> 6, b = blockIdx.x;

  // prefetch both units' packs (in flight during the offset work)
  const uu2 pk0 = pack[((size_t)b * 8 + w * 2 + 0) * 64 + lane];
  const uu2 pk1 = pack[((size_t)b * 8 + w * 2 + 1) * 64 + lane];
  float f = (lane < 8) ? fine[b * 8 + lane] : 0.0f;
  const float org = *origin;

  // block-exclusive prefix over coarse[0..b): <=16 coalesced L2/L3-hot iters
  float p = 0.0f;
  for (int i = t; i < b; i += BLOCK) p += coarse[i];
#pragma unroll
  for (int off = 32; off >= 1; off >>= 1) p += __shfl_xor(p, off, 64);
  if (lane == 0) ws2[w] = p;

  // in-block unit offsets: inclusive 8-lane shfl scan of fine (no LDS dep)
#pragma unroll
  for (int off = 1; off < 8; off <<= 1) {
    float y = __shfl_up(f, off, 64);
    if (lane >= off && lane < 8) f += y;
  }

  __syncthreads();                       // covers cs[] and ws2[]
  const float P = org + ws2[0] + ws2[1] + ws2[2] + ws2[3];

  if (b == nb - 1 && w == 0 && lane == 7)
    out[(size_t)nb * BPB] = P + f;       // out[N] = origin + grand total

  const uu2 pks[2] = {pk0, pk1};
#pragma unroll
  for (int h = 0; h < 2; ++h) {
    const int j = w * 2 + h;             // unit index within block (0..7)
    float carry = P + ((j > 0) ? __shfl(f, j - 1, 64) : 0.0f);
    const uu2 pk = pks[h];
    const size_t ubase = (size_t)b * BPB + (size_t)j * 1024;
#pragma unroll
    for (int r = 0; r < 4; ++r) {
      const unsigned pw = (r < 2) ? pk.x : pk.y;
      const unsigned us = (r & 1) ? (pw >> 16) : (pw & 0xFFFFu);
      const float v0 = cs[us & 0xFu];
      const float v1 = cs[(us >> 4) & 0xFu];
      const float v2 = cs[(us >> 8) & 0xFu];
      const float v3 = cs[(us >> 12) & 0xFu];
      const float s4 = v0 + v1 + v2 + v3;
      float x = s4;                      // inclusive wave scan of 4-elem sums
#pragma unroll
      for (int off = 1; off < 64; off <<= 1) {
        float y = __shfl_up(x, off, 64);
        if (lane >= off) x += y;
      }
      const float off0 = carry + (x - s4);
      f4 o;
      o.x = off0;
      o.y = off0 + v0;
      o.z = o.y + v1;
      o.w = o.z + v2;
      *((f4*)(out + ubase + r * 256 + lane * 4)) = o;   // PLAIN store (A/B)
      carry += __shfl(x, 63, 64);        // round total -> next round
    }
  }
}

extern "C" void kernel_launch(void* const* d_in, const int* in_sizes, int n_in,
                              void* d_out, int out_size, void* d_ws, size_t ws_size,
                              hipStream_t stream) {
  const int*   ann    = (const int*)d_in[0];
  const float* origin = (const float*)d_in[1];
  const float* bd     = (const float*)d_in[2];
  const float* dw     = (const float*)d_in[3];
  const float* sw     = (const float*)d_in[4];
  const float* ic     = (const float*)d_in[5];
  const float* bi     = (const float*)d_in[6];
  float* out = (float*)d_out;

  const int N  = in_sizes[0];   // 2^25
  const int nb = N / BPB;       // 4096 blocks

  float* coarse = (float*)d_ws;                 // 4096 floats
  float* fine   = coarse + 4096;                // 32768 floats
  uu2*   pack   = (uu2*)(fine + 32768);         // 16.8 MB

  k_pack_reduce<<<nb, BLOCK, 0, stream>>>(ann, bd, dw, sw, ic, bi,
                                          pack, coarse, fine);
  k_scan_out<<<nb, BLOCK, 0, stream>>>(pack, coarse, fine, origin,
                                       bd, dw, sw, ic, bi, out, nb);
}